// Round 5
// baseline (506.770 us; speedup 1.0000x reference)
//
#include <hip/hip_runtime.h>

#define NROW 16384
#define ROWI 10246
#define XB_W 160                 // 64-col bit-words per row (cols [0,10240))
#define NSPLIT 16
#define NSLICE 16                // D: slices 0..2, A: slices 3..15
#define POUT_F (NSLICE*33*16384)
#define WT_F   (ROWI*32)
#define PTAB_ROWS 3438
#define PTAB_F (PTAB_ROWS*64)

// k1 split tables (word0, nwords). D words [1,34) -> 3 splits; A words [35,160) -> 13 splits.
// Word 0 (cols 0..63), word 34 (cols 2176..2239) and cols 10240..10245 are handled in k2.
__device__ __constant__ int SPL_W0[NSPLIT] =
  {1, 12, 23, 35, 45, 55, 65, 75, 85, 95, 105, 115, 125, 135, 144, 152};
__device__ __constant__ int SPL_NW[NSPLIT] =
  {11, 11, 11, 10, 10, 10, 10, 10, 10, 10, 10, 10, 10, 9, 8, 8};

typedef unsigned long long u64;
typedef unsigned int u32;

// ---------------- prep kernels ----------------
__global__ void prep_wt(const float* __restrict__ Wg, const float* __restrict__ Wd,
                        const float* __restrict__ Wa, float* __restrict__ Wt) {
  int e = blockIdx.x*256 + threadIdx.x;
  if (e >= WT_F) return;
  int c = e >> 5, d = e & 31;
  float v = 0.f;
  if (c >= 1 && c < 26)         v = Wg[d*25   + (c-1)];
  else if (c >= 26 && c < 2212) v = Wd[d*2186 + (c-26)];
  else if (c >= 2212 && c < 10242) v = Wa[d*8030 + (c-2212)];
  Wt[e] = v;
}

__global__ void prep_p(const float* __restrict__ er, const float* __restrict__ eg,
                       const float* __restrict__ ea, const float* __restrict__ eo,
                       const float* __restrict__ ez, const float* __restrict__ W1,
                       float* __restrict__ P) {
  int id = blockIdx.x*256 + threadIdx.x;
  if (id >= PTAB_F) return;
  int r = id >> 6, o = id & 63;
  const float* emb; int woff;
  if (r < 6)       { emb = er + r*32;       woff = 0;   }
  else if (r < 8)  { emb = eg + (r-6)*32;   woff = 128; }
  else if (r < 15) { emb = ea + (r-8)*32;   woff = 160; }
  else if (r < 36) { emb = eo + (r-15)*32;  woff = 192; }
  else             { emb = ez + (r-36)*32;  woff = 224; }
  const float* w = W1 + o*256 + woff;
  float s = 0.f;
  #pragma unroll
  for (int c2 = 0; c2 < 32; ++c2) s += emb[c2]*w[c2];
  P[id] = s;
}

__global__ void prep_w2t(const float* __restrict__ W2, float* __restrict__ W2t) {
  int id = blockIdx.x*256 + threadIdx.x;
  if (id >= 64*64) return;
  int o = id >> 6, o2 = id & 63;
  W2t[o*64 + o2] = W2[o2*64 + o];
}

// ---------------- bit-pack kernel: x (0/1 int32) -> per-row 64-col bitmasks ----
// Coalesced pure stream: wave = one row, lane = col within word; ballot -> bits.
__global__ __launch_bounds__(256) void pack(const int* __restrict__ x,
                                            u64* __restrict__ xb) {
  const int lane = threadIdx.x & 63;
  const int r = blockIdx.x*4 + (threadIdx.x >> 6);
  const int* base = x + (size_t)r*ROWI;
  u64* orow = xb + (size_t)r*XB_W;
  #pragma unroll
  for (int grp = 0; grp < 3; ++grp) {
    const int wbeg = grp*64;
    const int wcnt = (grp == 2) ? 32 : 64;
    u32 slo = 0, shi = 0;
    for (int w8 = 0; w8 < wcnt; w8 += 8) {
      #pragma unroll
      for (int k = 0; k < 8; ++k) {
        const int wl = w8 + k;                    // word index within group
        const int v = base[(wbeg + wl)*64 + lane]; // coalesced 256B per instr
        const u64 b = __ballot(v != 0);            // bit l = row-col (wbeg+wl)*64+l... lane l
        if (lane == wl) { slo = (u32)b; shi = (u32)(b >> 32); }
      }
    }
    if (lane < wcnt)
      orow[wbeg + lane] = ((u64)shi << 32) | slo;  // coalesced 8B/lane store
  }
}

// ---------------- main accumulation kernel (VALU-bound, no staging) ----------
__global__ __launch_bounds__(256, 4) void k1(
    const u64* __restrict__ xb, const float* __restrict__ Wt,
    float* __restrict__ pout) {
  const int lane  = threadIdx.x & 63;
  const int wave  = threadIdx.x >> 6;
  const int split = blockIdx.y;
  const int rb    = blockIdx.x*4 + wave;     // 64-row block
  const int row   = rb*64 + lane;
  const int w0 = SPL_W0[split], nw = SPL_NW[split];
  const u64* xrow = xb + (size_t)row*XB_W;   // per-lane bit row

  float acc[32];
  int cntb = 0;
  #pragma unroll
  for (int d = 0; d < 32; ++d) acc[d] = 0.f;

  for (int w = w0; w < w0 + nw; ++w) {
    const u64 bits = xrow[w];                // 8B per lane (L2-resident, 21MB total)
    cntb += __popcll(bits);
    const u32 lo = (u32)bits, hi = (u32)(bits >> 32);
    const float* wb = Wt + (size_t)(w*64)*32; // wave-uniform -> scalar stream
    #pragma unroll
    for (int cc = 0; cc < 64; ++cc) {
      const u32 word = (cc < 32) ? lo : hi;
      const float xf = (float)((word >> (cc & 31)) & 1u);  // v_bfe + v_cvt
      const float* wc = wb + cc*32;
      #pragma unroll
      for (int d = 0; d < 32; ++d)
        acc[d] = fmaf(xf, wc[d], acc[d]);
    }
  }

  float* _p = pout + (size_t)split*33*16384;  // slice = split, d-major
  #pragma unroll
  for (int d = 0; d < 32; ++d) _p[(size_t)d*16384 + row] = acc[d];
  _p[(size_t)32*16384 + row] = (float)cntb;
}

// ---------------- boundary + reduce + MLP kernel ----------------
__global__ __launch_bounds__(64, 1) void k2(
    const int* __restrict__ x, const float* __restrict__ pout,
    const float* __restrict__ Wt, const float* __restrict__ P,
    const float* __restrict__ W1, const float* __restrict__ b1,
    const float* __restrict__ W2t, const float* __restrict__ b2,
    const float* __restrict__ Wout, const float* __restrict__ bout,
    float* __restrict__ out) {
  const int row = blockIdx.x*64 + threadIdx.x;
  const int* xr = x + (size_t)row*ROWI;

#define PSL(SL, D) pout[(size_t)((SL)*33 + (D))*16384 + row]

  float mG[32], mD[32], mA[32];
  float cG = 0.f, cD = 0.f, cA = 0.f;
  #pragma unroll
  for (int d = 0; d < 32; ++d) {
    mG[d] = 0.f;
    mD[d] = PSL(0, d) + PSL(1, d) + PSL(2, d);
    float s = 0.f;
    #pragma unroll
    for (int k = 3; k < 16; ++k) s += PSL(k, d);
    mA[d] = s;
  }
  cD = PSL(0, 32) + PSL(1, 32) + PSL(2, 32);
  #pragma unroll
  for (int k = 3; k < 16; ++k) cA += PSL(k, 32);

  // boundary words: cols [0,64) and [2176,2240) from raw x (compile-time bases)
#define BPART(CBASE) do {                                                      \
    int xbv[64];                                                               \
    _Pragma("unroll")                                                          \
    for (int i = 0; i < 32; ++i) {                                             \
      int2 v = *(const int2*)&xr[(CBASE) + 2*i];                               \
      xbv[2*i] = v.x; xbv[2*i+1] = v.y;                                        \
    }                                                                          \
    _Pragma("unroll")                                                          \
    for (int c2 = 0; c2 < 64; ++c2) {                                          \
      const int c = (CBASE) + c2;                                              \
      if (c == 0) continue;                                                    \
      const float xf = (float)xbv[c2];                                         \
      const float* w = Wt + (size_t)c*32;                                      \
      if (c < 26) { cG += xf;                                                  \
        _Pragma("unroll")                                                      \
        for (int d = 0; d < 32; ++d) mG[d] = fmaf(xf, w[d], mG[d]);            \
      } else if (c < 2212) { cD += xf;                                         \
        _Pragma("unroll")                                                      \
        for (int d = 0; d < 32; ++d) mD[d] = fmaf(xf, w[d], mD[d]);            \
      } else { cA += xf;                                                       \
        _Pragma("unroll")                                                      \
        for (int d = 0; d < 32; ++d) mA[d] = fmaf(xf, w[d], mA[d]);            \
      }                                                                        \
    } } while (0)

  BPART(0);
  BPART(2176);
#undef BPART

  // tail columns 10240, 10241 (actor)
  {
    const float t0 = (float)xr[10240], t1 = (float)xr[10241];
    cA += t0 + t1;
    #pragma unroll
    for (int d = 0; d < 32; ++d)
      mA[d] = fmaf(t1, Wt[10241*32+d], fmaf(t0, Wt[10240*32+d], mA[d]));
  }

  #pragma unroll
  for (int d = 0; d < 32; ++d) { mG[d] /= cG; mD[d] /= cD; mA[d] /= cA; }

  // index-embedding contributions via folded P table
  const int ridx = xr[0];
  const int gi = xr[10242], ai = xr[10243], oi = xr[10244], ari = xr[10245];
  const float* Pr = P + (size_t)ridx*64;
  const float* Pg = P + (size_t)(6 + gi)*64;
  const float* Pa = P + (size_t)(8 + ai)*64;
  const float* Po = P + (size_t)(15 + oi)*64;
  const float* Pz = P + (size_t)(36 + ari)*64;

  float h1[64];
  #pragma unroll
  for (int o = 0; o < 64; ++o)
    h1[o] = b1[o] + ((Pr[o] + Pg[o]) + (Pa[o] + Po[o])) + Pz[o];

  #pragma unroll
  for (int o = 0; o < 64; ++o) {
    const float* w = W1 + o*256;
    float a = h1[o];
    #pragma unroll
    for (int d = 0; d < 32; ++d) a = fmaf(mG[d], w[32+d], a);
    #pragma unroll
    for (int d = 0; d < 32; ++d) a = fmaf(mD[d], w[64+d], a);
    #pragma unroll
    for (int d = 0; d < 32; ++d) a = fmaf(mA[d], w[96+d], a);
    h1[o] = fmaxf(a, 0.f);
  }

  float h2[64];
  #pragma unroll
  for (int o2 = 0; o2 < 64; ++o2) h2[o2] = b2[o2];
  #pragma unroll
  for (int o = 0; o < 64; ++o) {
    const float h = h1[o];
    const float* wr = W2t + o*64;
    #pragma unroll
    for (int o2 = 0; o2 < 64; ++o2) h2[o2] = fmaf(h, wr[o2], h2[o2]);
  }
  float acc = bout[0];
  #pragma unroll
  for (int o2 = 0; o2 < 64; ++o2) acc = fmaf(fmaxf(h2[o2], 0.f), Wout[o2], acc);
  out[row] = acc;
#undef PSL
}

// ---------------- launcher ----------------
extern "C" void kernel_launch(void* const* d_in, const int* in_sizes, int n_in,
                              void* d_out, int out_size, void* d_ws, size_t ws_size,
                              hipStream_t stream) {
  (void)in_sizes; (void)n_in; (void)out_size; (void)ws_size;
  const int*   x        = (const int*)  d_in[0];
  const float* emb_rate = (const float*)d_in[1];
  const float* W_genre  = (const float*)d_in[2];
  const float* W_dir    = (const float*)d_in[3];
  const float* W_actor  = (const float*)d_in[4];
  const float* emb_gen  = (const float*)d_in[5];
  const float* emb_age  = (const float*)d_in[6];
  const float* emb_occ  = (const float*)d_in[7];
  const float* emb_area = (const float*)d_in[8];
  const float* W1   = (const float*)d_in[9];
  const float* b1   = (const float*)d_in[10];
  const float* W2   = (const float*)d_in[11];
  const float* b2   = (const float*)d_in[12];
  const float* Wout = (const float*)d_in[13];
  const float* bout = (const float*)d_in[14];
  float* outp = (float*)d_out;

  float* ws   = (float*)d_ws;
  float* pout = ws;
  u64*   xb   = (u64*)(ws + POUT_F);          // POUT_F*4 bytes, 8B-aligned
  float* Wt   = (float*)(xb + (size_t)NROW*XB_W);
  float* P    = Wt + WT_F;
  float* W2t  = P + PTAB_F;

  prep_wt<<<(WT_F + 255)/256, 256, 0, stream>>>(W_genre, W_dir, W_actor, Wt);
  prep_p<<<(PTAB_F + 255)/256, 256, 0, stream>>>(emb_rate, emb_gen, emb_age, emb_occ,
                                                 emb_area, W1, P);
  prep_w2t<<<16, 256, 0, stream>>>(W2, W2t);

  pack<<<NROW/4, 256, 0, stream>>>(x, xb);

  dim3 g1(64, NSPLIT);
  k1<<<g1, 256, 0, stream>>>(xb, Wt, pout);
  k2<<<256, 64, 0, stream>>>(x, pout, Wt, P, W1, b1, W2t, b2, Wout, bout, outp);
}

// Round 6
// 328.264 us; speedup vs baseline: 1.5438x; 1.5438x over previous
//
#include <hip/hip_runtime.h>

#define NROW 16384
#define ROWI 10246
#define NSLICE 6                  // [half][seg]: h*3 + {G,D,A}
#define POUT_F (NSLICE*33*16384)
#define NSLOT 323                 // B-frag slots: 0..320 tiles, 321=D@t0, 322=A@t69
#define BF_U16 ((size_t)NSLOT*128*8)
#define PTAB_ROWS 3438
#define PTAB_F (PTAB_ROWS*64)

typedef unsigned int u32;
typedef unsigned short u16;
typedef short short8 __attribute__((ext_vector_type(8)));
typedef float f32x4 __attribute__((ext_vector_type(4)));

union AFrag { u32 u[4]; short8 s; };
union BFrag { uint4 v; short8 s; };

// ---------------- prep: B fragment table (bf16, MFMA layout) ----------------
// Frag id = (slot*2 + f)*64 + lane ; elem e: k = t*32 + (lane>>4)*8 + e,
// d = f*16 + (lane&15). Masked to the slot's segment (zeros elsewhere).
__global__ void prep_bf(const float* __restrict__ Wg, const float* __restrict__ Wd,
                        const float* __restrict__ Wa, u16* __restrict__ Bf) {
  int id = blockIdx.x*256 + threadIdx.x;
  if (id >= NSLOT*128) return;
  int lane = id & 63, f = (id >> 6) & 1, slot = id >> 7;
  int t   = (slot == 321) ? 0 : (slot == 322) ? 69 : slot;
  int seg = (slot == 0) ? 0 : (slot <= 69) ? 1 : (slot <= 320) ? 2
            : (slot == 321) ? 1 : 2;                  // 0=G,1=D,2=A
  int clo = (seg == 0) ? 1  : (seg == 1) ? 26   : 2212;
  int chi = (seg == 0) ? 26 : (seg == 1) ? 2212 : 10242;
  int d  = f*16 + (lane & 15);
  int kb = t*32 + (lane >> 4)*8;
  u16 o[8];
  #pragma unroll
  for (int e = 0; e < 8; ++e) {
    int c = kb + e;
    float v = 0.f;
    if (c >= clo && c < chi) {
      if (seg == 0)      v = Wg[d*25   + (c-1)];
      else if (seg == 1) v = Wd[d*2186 + (c-26)];
      else               v = Wa[d*8030 + (c-2212)];
    }
    u32 bits = __float_as_uint(v);                    // RNE float->bf16
    o[e] = (u16)((bits + 0x7FFFu + ((bits >> 16) & 1u)) >> 16);
  }
  uint4 w;
  w.x = (u32)o[0] | ((u32)o[1] << 16);
  w.y = (u32)o[2] | ((u32)o[3] << 16);
  w.z = (u32)o[4] | ((u32)o[5] << 16);
  w.w = (u32)o[6] | ((u32)o[7] << 16);
  *(uint4*)&Bf[(size_t)id*8] = w;
}

// ---------------- prep: folded index-embedding table ----------------
__global__ void prep_p(const float* __restrict__ er, const float* __restrict__ eg,
                       const float* __restrict__ ea, const float* __restrict__ eo,
                       const float* __restrict__ ez, const float* __restrict__ W1,
                       float* __restrict__ P) {
  int id = blockIdx.x*256 + threadIdx.x;
  if (id >= PTAB_F) return;
  int r = id >> 6, o = id & 63;
  const float* emb; int woff;
  if (r < 6)       { emb = er + r*32;       woff = 0;   }
  else if (r < 8)  { emb = eg + (r-6)*32;   woff = 128; }
  else if (r < 15) { emb = ea + (r-8)*32;   woff = 160; }
  else if (r < 36) { emb = eo + (r-15)*32;  woff = 192; }
  else             { emb = ez + (r-36)*32;  woff = 224; }
  const float* w = W1 + o*256 + woff;
  float s = 0.f;
  #pragma unroll
  for (int c2 = 0; c2 < 32; ++c2) s += emb[c2]*w[c2];
  P[id] = s;
}

__global__ void prep_w2t(const float* __restrict__ W2, float* __restrict__ W2t) {
  int id = blockIdx.x*256 + threadIdx.x;
  if (id >= 64*64) return;
  int o = id >> 6, o2 = id & 63;
  W2t[o*64 + o2] = W2[o2*64 + o];
}

// ---------------- fused stream + MFMA bag kernel ----------------
// Wave = 16 rows; block = 4 waves = 64 rows; blockIdx.y = K-half (tiles [0,160)/[160,320)).
// A: lane row = l&15, k = (l>>4)*8+e.  B frags from table.  D: d = l&15 (+16), row = (l>>4)*4+reg.
__global__ __launch_bounds__(256, 2) void kmain(
    const int* __restrict__ x, const u16* __restrict__ Bf, float* __restrict__ pout) {
  const int lane = threadIdx.x & 63;
  const int wv   = threadIdx.x >> 6;
  const int half = blockIdx.y;
  const int row0w = blockIdx.x*64 + wv*16;
  const int r = lane & 15, g = lane >> 4;

  const int tb = half*160, te = tb + 160;

  const int2* pA = (const int2*)(x + (size_t)(row0w + r)*ROWI) + g*4;  // + t*16 + j
  const uint4* pB = (const uint4*)Bf;                                  // frag id

  f32x4 aG0={0.f,0.f,0.f,0.f}, aG1=aG0, aD0=aG0, aD1=aG0, aA0=aG0, aA1=aG0;
  int cG = 0, cD = 0, cA = 0;

  int2 aC[4], aN1[4], aN2[4];
  uint4 bC0, bC1, bN0, bN1;
  #pragma unroll
  for (int j = 0; j < 4; ++j) { aC[j] = pA[tb*16 + j]; aN1[j] = pA[(tb+1)*16 + j]; }
  bC0 = pB[(tb*2)*64 + lane];
  bC1 = pB[(tb*2+1)*64 + lane];

  for (int t = tb; t < te; ++t) {
    if (t + 2 < te) {
      #pragma unroll
      for (int j = 0; j < 4; ++j) aN2[j] = pA[(t+2)*16 + j];
    }
    if (t + 1 < te) {
      bN0 = pB[((t+1)*2)*64 + lane];
      bN1 = pB[((t+1)*2+1)*64 + lane];
    }

    AFrag af; int csum = 0;
    #pragma unroll
    for (int j = 0; j < 4; ++j) {
      const int lo = aC[j].x, hi = aC[j].y;
      af.u[j] = (u32)(lo + (hi << 16)) * 0x3F80u;   // two 0/1 ints -> two bf16
      csum += lo + hi;
    }
    BFrag b0, b1; b0.v = bC0; b1.v = bC1;

    if (t == 0) {
      aG0 = __builtin_amdgcn_mfma_f32_16x16x32_bf16(af.s, b0.s, aG0, 0, 0, 0);
      aG1 = __builtin_amdgcn_mfma_f32_16x16x32_bf16(af.s, b1.s, aG1, 0, 0, 0);
      BFrag e0, e1;
      e0.v = pB[(321*2)*64 + lane];
      e1.v = pB[(321*2+1)*64 + lane];
      aD0 = __builtin_amdgcn_mfma_f32_16x16x32_bf16(af.s, e0.s, aD0, 0, 0, 0);
      aD1 = __builtin_amdgcn_mfma_f32_16x16x32_bf16(af.s, e1.s, aD1, 0, 0, 0);
      #pragma unroll
      for (int j = 0; j < 4; ++j) {                 // cols g*8+2j(+1): G=[1,26) D=[26,32)
        const int c0 = g*8 + 2*j, c1 = c0 + 1;
        const int v0 = aC[j].x, v1 = aC[j].y;
        cG += (c0 >= 1 && c0 < 26) ? v0 : 0;
        cG += (c1 < 26) ? v1 : 0;
        cD += (c0 >= 26) ? v0 : 0;
        cD += (c1 >= 26) ? v1 : 0;
      }
    } else if (t < 70) {
      aD0 = __builtin_amdgcn_mfma_f32_16x16x32_bf16(af.s, b0.s, aD0, 0, 0, 0);
      aD1 = __builtin_amdgcn_mfma_f32_16x16x32_bf16(af.s, b1.s, aD1, 0, 0, 0);
      if (t == 69) {                                // cols 2208..2211 D, 2212..2239 A
        BFrag e0, e1;
        e0.v = pB[(322*2)*64 + lane];
        e1.v = pB[(322*2+1)*64 + lane];
        aA0 = __builtin_amdgcn_mfma_f32_16x16x32_bf16(af.s, e0.s, aA0, 0, 0, 0);
        aA1 = __builtin_amdgcn_mfma_f32_16x16x32_bf16(af.s, e1.s, aA1, 0, 0, 0);
        #pragma unroll
        for (int j = 0; j < 4; ++j) {               // D iff g==0 && e<4 (i.e. j<2)
          const int s01 = aC[j].x + aC[j].y;
          if (j < 2) { cD += (g == 0) ? s01 : 0; cA += (g == 0) ? 0 : s01; }
          else       { cA += s01; }
        }
      } else {
        cD += csum;
      }
    } else {
      aA0 = __builtin_amdgcn_mfma_f32_16x16x32_bf16(af.s, b0.s, aA0, 0, 0, 0);
      aA1 = __builtin_amdgcn_mfma_f32_16x16x32_bf16(af.s, b1.s, aA1, 0, 0, 0);
      cA += csum;
    }

    #pragma unroll
    for (int j = 0; j < 4; ++j) { aC[j] = aN1[j]; aN1[j] = aN2[j]; }
    bC0 = bN0; bC1 = bN1;
  }

  // full per-row counts: reduce over the 4 k-groups (lanes l, l^16, l^32, l^48)
  cG += __shfl_xor(cG, 16); cG += __shfl_xor(cG, 32);
  cD += __shfl_xor(cD, 16); cD += __shfl_xor(cD, 32);
  cA += __shfl_xor(cA, 16); cA += __shfl_xor(cA, 32);

  const int sl0 = half*3;
#define STO(A0, A1, SL) do {                                                   \
    float* bp = pout + (size_t)(SL)*33*16384;                                  \
    _Pragma("unroll")                                                          \
    for (int q = 0; q < 4; ++q) {                                              \
      bp[(size_t)r*16384      + row0w + g*4 + q] = A0[q];                      \
      bp[(size_t)(16+r)*16384 + row0w + g*4 + q] = A1[q];                      \
    } } while (0)
  STO(aG0, aG1, sl0+0);
  STO(aD0, aD1, sl0+1);
  STO(aA0, aA1, sl0+2);
#undef STO
  if (lane < 16) {
    pout[((size_t)(sl0+0)*33 + 32)*16384 + row0w + lane] = (float)cG;
    pout[((size_t)(sl0+1)*33 + 32)*16384 + row0w + lane] = (float)cD;
    pout[((size_t)(sl0+2)*33 + 32)*16384 + row0w + lane] = (float)cA;
  }
}

// ---------------- reduce + tail + MLP kernel ----------------
__global__ __launch_bounds__(64, 1) void k2(
    const int* __restrict__ x, const float* __restrict__ pout,
    const float* __restrict__ Wa, const float* __restrict__ P,
    const float* __restrict__ W1, const float* __restrict__ b1,
    const float* __restrict__ W2t, const float* __restrict__ b2,
    const float* __restrict__ Wout, const float* __restrict__ bout,
    float* __restrict__ out) {
  const int row = blockIdx.x*64 + threadIdx.x;
  const int* xr = x + (size_t)row*ROWI;

#define PSL(SL, D) pout[(size_t)((SL)*33 + (D))*16384 + row]
  float mG[32], mD[32], mA[32];
  #pragma unroll
  for (int d = 0; d < 32; ++d) {
    mG[d] = PSL(0, d) + PSL(3, d);
    mD[d] = PSL(1, d) + PSL(4, d);
    mA[d] = PSL(2, d) + PSL(5, d);
  }
  float cG = PSL(0, 32) + PSL(3, 32);
  float cD = PSL(1, 32) + PSL(4, 32);
  float cA = PSL(2, 32) + PSL(5, 32);
#undef PSL

  // tail actor columns 10240, 10241 (= Wa cols 8028, 8029)
  {
    const float t0 = (float)xr[10240], t1 = (float)xr[10241];
    cA += t0 + t1;
    #pragma unroll
    for (int d = 0; d < 32; ++d)
      mA[d] = fmaf(t1, Wa[d*8030 + 8029], fmaf(t0, Wa[d*8030 + 8028], mA[d]));
  }

  #pragma unroll
  for (int d = 0; d < 32; ++d) { mG[d] /= cG; mD[d] /= cD; mA[d] /= cA; }

  const int ridx = xr[0];
  const int gi = xr[10242], ai = xr[10243], oi = xr[10244], ari = xr[10245];
  const float* Pr = P + (size_t)ridx*64;
  const float* Pg = P + (size_t)(6 + gi)*64;
  const float* Pa = P + (size_t)(8 + ai)*64;
  const float* Po = P + (size_t)(15 + oi)*64;
  const float* Pz = P + (size_t)(36 + ari)*64;

  float h1[64];
  #pragma unroll
  for (int o = 0; o < 64; ++o)
    h1[o] = b1[o] + ((Pr[o] + Pg[o]) + (Pa[o] + Po[o])) + Pz[o];

  #pragma unroll
  for (int o = 0; o < 64; ++o) {
    const float* w = W1 + o*256;
    float a = h1[o];
    #pragma unroll
    for (int d = 0; d < 32; ++d) a = fmaf(mG[d], w[32+d], a);
    #pragma unroll
    for (int d = 0; d < 32; ++d) a = fmaf(mD[d], w[64+d], a);
    #pragma unroll
    for (int d = 0; d < 32; ++d) a = fmaf(mA[d], w[96+d], a);
    h1[o] = fmaxf(a, 0.f);
  }

  float h2[64];
  #pragma unroll
  for (int o2 = 0; o2 < 64; ++o2) h2[o2] = b2[o2];
  #pragma unroll
  for (int o = 0; o < 64; ++o) {
    const float h = h1[o];
    const float* wr = W2t + o*64;
    #pragma unroll
    for (int o2 = 0; o2 < 64; ++o2) h2[o2] = fmaf(h, wr[o2], h2[o2]);
  }
  float acc = bout[0];
  #pragma unroll
  for (int o2 = 0; o2 < 64; ++o2) acc = fmaf(fmaxf(h2[o2], 0.f), Wout[o2], acc);
  out[row] = acc;
}

// ---------------- launcher ----------------
extern "C" void kernel_launch(void* const* d_in, const int* in_sizes, int n_in,
                              void* d_out, int out_size, void* d_ws, size_t ws_size,
                              hipStream_t stream) {
  (void)in_sizes; (void)n_in; (void)out_size; (void)ws_size;
  const int*   x        = (const int*)  d_in[0];
  const float* emb_rate = (const float*)d_in[1];
  const float* W_genre  = (const float*)d_in[2];
  const float* W_dir    = (const float*)d_in[3];
  const float* W_actor  = (const float*)d_in[4];
  const float* emb_gen  = (const float*)d_in[5];
  const float* emb_age  = (const float*)d_in[6];
  const float* emb_occ  = (const float*)d_in[7];
  const float* emb_area = (const float*)d_in[8];
  const float* W1   = (const float*)d_in[9];
  const float* b1   = (const float*)d_in[10];
  const float* W2   = (const float*)d_in[11];
  const float* b2   = (const float*)d_in[12];
  const float* Wout = (const float*)d_in[13];
  const float* bout = (const float*)d_in[14];
  float* outp = (float*)d_out;

  float* ws   = (float*)d_ws;
  float* pout = ws;                                   // 6*33*16384 floats
  u16*   Bf   = (u16*)(ws + POUT_F);                  // 323*128*8 u16 (16B-aligned)
  float* P    = (float*)(Bf + BF_U16);
  float* W2t  = P + PTAB_F;

  prep_bf<<<(NSLOT*128 + 255)/256, 256, 0, stream>>>(W_genre, W_dir, W_actor, Bf);
  prep_p<<<(PTAB_F + 255)/256, 256, 0, stream>>>(emb_rate, emb_gen, emb_age, emb_occ,
                                                 emb_area, W1, P);
  prep_w2t<<<16, 256, 0, stream>>>(W2, W2t);

  dim3 gm(NROW/64, 2);
  kmain<<<gm, 256, 0, stream>>>(x, Bf, pout);
  k2<<<NROW/64, 64, 0, stream>>>(x, pout, W_actor, P, W1, b1, W2t, b2, Wout, bout, outp);
}